// Round 5
// baseline (42.105 us; speedup 1.0000x reference)
//
#include <hip/hip_runtime.h>

// Conv2d 16->16, k=3, stride 1, pad 1, H=W=1024.
// Round 6: asm-pinned staging loads + fused weight prep.
//   Rounds 1-5 post-mortem: time pinned at 39-46us across five structures
//   while VGPR_Count (68/116/36/60) proves hipcc NEVER kept the 16-load
//   staging batch live -- it interleaves load->pack, leaving ~4 loads in
//   flight/thread, and sinks prefetches to their use (guide Common-mistake
//   #1/#5: source-level scheduling loses). Sustained read MLP ~ 12-24KB/CU
//   only during stage phases -> 3-3.5 TB/s reproduces all rounds.
//   Fix: issue 16 global_load_dwordx4 via asm volatile (saddr form: 16
//   uniform SGPR plane bases + one per-thread voffset), early-clobber
//   outputs pinned in VGPRs, explicit s_waitcnt vmcnt(0) + sched_barrier(0)
//   (rule #18) before pack. Also fold conv_prep into the kernel (weights
//   gathered per-thread from L2) to drop the second dispatch.
//   Geometry unchanged from R5 (verified): TW=128, TH=8, LDS [y][x][ci]
//   bf16 w/ 2-bit XOR swizzle, K=160 = 5 x mfma_f32_16x16x32_bf16,
//   D[px][co] -> float4 stores. Grid 8x128; bx == XCD id so vertical
//   halo neighbors share an L2.

#define H 1024
#define W 1024
#define HW (H * W)
#define TW 128
#define TH 8
#define LROWS 10             // TH + 2 halo rows
#define NQ 34                // float4-quads per halo row ([colbase-4, colbase+132))
#define NJOBS (LROWS * NQ)   // 340
#define LCOLS 130            // staged cols: lx in [0, 130)
#define LPITCH (LCOLS * 32)  // 4160 B (32 B per col = 16 ci * 2 B)
#define LDS_BYTES (LROWS * LPITCH)   // 41600

typedef __bf16 bf16x8 __attribute__((ext_vector_type(8)));
typedef float f32x4 __attribute__((ext_vector_type(4)));
typedef unsigned short ushort8 __attribute__((ext_vector_type(8)));
typedef unsigned int uint4v __attribute__((ext_vector_type(4)));

__device__ __host__ inline unsigned short f2bf(float f) {
  unsigned u = __builtin_bit_cast(unsigned, f);
  return (unsigned short)((u + 0x7fffu + ((u >> 16) & 1u)) >> 16);  // RNE
}

// One staging job: 4 cols x 16 channels. 16 asm-pinned global_load_dwordx4
// (saddr = uniform plane base, voffset = per-thread pixel), wait, pack
// fp32->bf16 pairs, 8 x ds_write_b128.
__device__ __forceinline__ void stage_job(int j, const float* __restrict__ x,
                                          int colbase, int rowbase, char* lds) {
  const int ly  = j / NQ;            // 0..9
  const int qx  = j - ly * NQ;       // 0..33
  const int gy  = rowbase - 1 + ly;
  const float rowm = ((unsigned)gy < (unsigned)H) ? 1.f : 0.f;
  const int gyc  = gy < 0 ? 0 : (gy > H - 1 ? H - 1 : gy);
  const int gx0  = colbase - 4 + 4 * qx;
  const int gx0c = gx0 < 0 ? 0 : (gx0 > W - 4 ? W - 4 : gx0);
  const unsigned voff = (unsigned)((gyc * W + gx0c) * 4);  // bytes, ci-invariant

  f32x4 L[16];
  asm volatile(
      "global_load_dwordx4 %0, %8, %9\n\t"
      "global_load_dwordx4 %1, %8, %10\n\t"
      "global_load_dwordx4 %2, %8, %11\n\t"
      "global_load_dwordx4 %3, %8, %12\n\t"
      "global_load_dwordx4 %4, %8, %13\n\t"
      "global_load_dwordx4 %5, %8, %14\n\t"
      "global_load_dwordx4 %6, %8, %15\n\t"
      "global_load_dwordx4 %7, %8, %16\n\t"
      : "=&v"(L[0]), "=&v"(L[1]), "=&v"(L[2]), "=&v"(L[3]),
        "=&v"(L[4]), "=&v"(L[5]), "=&v"(L[6]), "=&v"(L[7])
      : "v"(voff), "s"(x), "s"(x + HW), "s"(x + 2 * HW), "s"(x + 3 * HW),
        "s"(x + 4 * HW), "s"(x + 5 * HW), "s"(x + 6 * HW), "s"(x + 7 * HW));
  asm volatile(
      "global_load_dwordx4 %0, %8, %9\n\t"
      "global_load_dwordx4 %1, %8, %10\n\t"
      "global_load_dwordx4 %2, %8, %11\n\t"
      "global_load_dwordx4 %3, %8, %12\n\t"
      "global_load_dwordx4 %4, %8, %13\n\t"
      "global_load_dwordx4 %5, %8, %14\n\t"
      "global_load_dwordx4 %6, %8, %15\n\t"
      "global_load_dwordx4 %7, %8, %16\n\t"
      : "=&v"(L[8]), "=&v"(L[9]), "=&v"(L[10]), "=&v"(L[11]),
        "=&v"(L[12]), "=&v"(L[13]), "=&v"(L[14]), "=&v"(L[15])
      : "v"(voff), "s"(x + 8 * HW), "s"(x + 9 * HW), "s"(x + 10 * HW),
        "s"(x + 11 * HW), "s"(x + 12 * HW), "s"(x + 13 * HW),
        "s"(x + 14 * HW), "s"(x + 15 * HW));

  // All 16 loads in flight; drain once, and fence VALU reordering (rule #18).
  asm volatile("s_waitcnt vmcnt(0)" ::: "memory");
  __builtin_amdgcn_sched_barrier(0);

#pragma unroll
  for (int i = 0; i < 4; ++i) {
    const int gx = gx0 + i;
    const int lx = gx - (colbase - 1);
    if ((unsigned)lx < (unsigned)LCOLS) {
      const float fm = rowm * (((unsigned)gx < (unsigned)W) ? 1.f : 0.f);
      const int lb = (ly * LPITCH + lx * 32) ^ (((lx >> 2) & 3) << 4);
#pragma unroll
      for (int h = 0; h < 2; ++h) {
        uint4v d;
#pragma unroll
        for (int p = 0; p < 4; ++p) {
          const unsigned lo = f2bf(L[h * 8 + 2 * p][i] * fm);
          const unsigned hi = f2bf(L[h * 8 + 2 * p + 1][i] * fm);
          d[p] = lo | (hi << 16);
        }
        *(uint4v*)(lds + (lb ^ (h << 4))) = d;
      }
    }
  }
}

__global__ __launch_bounds__(256) void conv_mfma(
    const float* __restrict__ x, const float* __restrict__ w,
    float* __restrict__ out) {
  __shared__ __align__(16) char lds[LDS_BYTES];

  const int tid  = threadIdx.x;
  const int lane = tid & 63;
  const int wave = tid >> 6;
  const int m = lane & 15;   // A row = pixel within 16-px group
  const int q = lane >> 4;   // k-quarter
  const int colbase = blockIdx.x * TW;
  const int rowbase = blockIdx.y * TH;

  // ---- stage: 340 jobs over 256 threads (second batch for tid<84) ----
  stage_job(tid, x, colbase, rowbase, lds);
  if (tid < NJOBS - 256) stage_job(256 + tid, x, colbase, rowbase, lds);

  // ---- weight fragments gathered in-kernel (w is 9 KB, L2-hot):
  // wU[p][j] for k=(lane>>4)*8+j: tap t = 2p+(q>>1), ci = (q&1)*8+j, co=m.
  ushort8 wU[5];
  {
    const int tq = q >> 1, ci0 = (q & 1) * 8;
#pragma unroll
    for (int p = 0; p < 5; ++p) {
      const int t = 2 * p + tq;
      ushort8 u;
#pragma unroll
      for (int j = 0; j < 8; ++j) {
        float v = (t <= 8) ? w[m * 144 + (ci0 + j) * 9 + t] : 0.f;
        u[j] = f2bf(v);
      }
      wU[p] = u;
    }
  }

  // ---- per-lane LDS read base addresses ----
  int baseaddr[5];
#pragma unroll
  for (int p = 0; p < 5; ++p) {
    int t = 2 * p + (q >> 1);
    int ky = 0, kx = 0;
    if (t <= 8) { ky = t / 3; kx = t - ky * 3; }  // t==9: valid addr, zero weights
    int col = m + kx;
    int b = ky * LPITCH + col * 32 + (q & 1) * 16;
    b ^= ((col >> 2) & 3) << 4;
    baseaddr[p] = b + wave * 2 * LPITCH;
  }

  __syncthreads();

  // ---- compute: wave -> rows wave*2..+1, 8 groups of 16 px per row ----
#pragma unroll
  for (int r = 0; r < 2; ++r) {
#pragma unroll
    for (int g = 0; g < 8; ++g) {
      f32x4 acc = {0.f, 0.f, 0.f, 0.f};
#pragma unroll
      for (int p = 0; p < 5; ++p) {
        ushort8 bU = *(const ushort8*)(lds + (baseaddr[p] + r * LPITCH + g * 512));
        acc = __builtin_amdgcn_mfma_f32_16x16x32_bf16(
            __builtin_bit_cast(bf16x8, bU),       // A = pixels
            __builtin_bit_cast(bf16x8, wU[p]),    // B = weights
            acc, 0, 0, 0);
      }
      // D: col = lane&15 = c_out, row = q*4+j = pixel -> float4 store of 4
      // consecutive pixels for one channel.
      const int y  = rowbase + wave * 2 + r;
      const int x0 = colbase + g * 16 + q * 4;
      *(f32x4*)(out + m * HW + y * W + x0) = acc;
    }
  }
}

extern "C" void kernel_launch(void* const* d_in, const int* in_sizes, int n_in,
                              void* d_out, int out_size, void* d_ws, size_t ws_size,
                              hipStream_t stream) {
  const float* x = (const float*)d_in[0];            // (1,16,1024,1024) fp32
  const float* w = (const float*)d_in[1];            // (16,16,3,3) fp32
  float* out = (float*)d_out;                        // (16,1024,1024) fp32

  dim3 grid(W / TW, H / TH);                         // 8 x 128 = 1024 blocks
  conv_mfma<<<grid, 256, 0, stream>>>(x, w, out);
}

// Round 6
// 37.095 us; speedup vs baseline: 1.1351x; 1.1351x over previous
//
#include <hip/hip_runtime.h>

// Conv2d 16->16, k=3, stride 1, pad 1, H=W=1024.
// Round 7: TLP test -- TH=4, 6 blocks/CU (24 waves), 1 staging job/thread.
//   Rounds 1-6 post-mortem: BW pinned at 2.7-3.7 TB/s across ILP depth
//   4->16 (asm-pinned, VGPR proves it), run length 256->544B, and four
//   schedules. Only correlate with BW: wave count (R2 ~14 waves/CU ->
//   3.3 TB/s; R5/R6 ~7 -> 2.8). m13's 6.3 TB/s copy saturates via TLP.
//   Under loaded latency ~2us a CU needs ~20KB sustained in flight;
//   at <=12 waves and ~1/3 stage duty we sustain half that -> ~45% of
//   HBM share, reproducing every round. Fix: TH=4 -> LDS 25KB -> 6
//   blocks/CU, short (~1.3us) blocks so stage/compute phases of ~6
//   blocks interleave continuously per CU.
//   Geometry otherwise unchanged from R5/R6 (verified): TW=128, LDS
//   [y][x][ci] bf16 w/ 2-bit XOR swizzle on byte bits 4-5, K=160 =
//   5 x mfma_f32_16x16x32_bf16, D[px][co] -> float4 stores, asm-pinned
//   16 x global_load_dwordx4 staging, grid-x = 8 = #XCDs.

#define H 1024
#define W 1024
#define HW (H * W)
#define TW 128
#define TH 4
#define LROWS 6              // TH + 2 halo rows
#define NQ 34                // float4-quads per halo row ([colbase-4, colbase+132))
#define NJOBS (LROWS * NQ)   // 204  (<= 256: one job per thread)
#define LCOLS 130            // staged cols: lx in [0, 130)
#define LPITCH (LCOLS * 32)  // 4160 B (32 B per col = 16 ci * 2 B)
#define LDS_BYTES (LROWS * LPITCH)   // 24960

typedef __bf16 bf16x8 __attribute__((ext_vector_type(8)));
typedef float f32x4 __attribute__((ext_vector_type(4)));
typedef unsigned short ushort8 __attribute__((ext_vector_type(8)));
typedef unsigned int uint4v __attribute__((ext_vector_type(4)));

__device__ __host__ inline unsigned short f2bf(float f) {
  unsigned u = __builtin_bit_cast(unsigned, f);
  return (unsigned short)((u + 0x7fffu + ((u >> 16) & 1u)) >> 16);  // RNE
}

// wA[p*512 + lane*8 + j]: weight fragment, col=co=lane&15, k=(lane>>4)*8+j;
// mfma p covers taps {2p, 2p+1}; tap = 2p + (k>>4), ci = k&15.
__global__ __launch_bounds__(256) void conv_prep(const float* __restrict__ w,
                                                 unsigned short* __restrict__ wA) {
  int i = blockIdx.x * 256 + threadIdx.x;
  if (i >= 5 * 64 * 8) return;
  int j = i & 7;
  int l = (i >> 3) & 63;
  int p = i >> 9;
  int k = (l >> 4) * 8 + j;
  int t = 2 * p + (k >> 4);
  int ci = k & 15;
  int co = l & 15;
  float v = (t <= 8) ? w[co * 144 + ci * 9 + t] : 0.f;  // w[co][ci][ky][kx], t=ky*3+kx
  wA[i] = f2bf(v);
}

// One staging job: 4 cols x 16 channels. 16 asm-pinned global_load_dwordx4
// (saddr = uniform plane base, voffset = per-thread pixel), single drain,
// pack fp32->bf16 pairs, 8 x ds_write_b128.
__device__ __forceinline__ void stage_job(int j, const float* __restrict__ x,
                                          int colbase, int rowbase, char* lds) {
  const int ly  = j / NQ;            // 0..LROWS-1
  const int qx  = j - ly * NQ;       // 0..33
  const int gy  = rowbase - 1 + ly;
  const float rowm = ((unsigned)gy < (unsigned)H) ? 1.f : 0.f;
  const int gyc  = gy < 0 ? 0 : (gy > H - 1 ? H - 1 : gy);
  const int gx0  = colbase - 4 + 4 * qx;
  const int gx0c = gx0 < 0 ? 0 : (gx0 > W - 4 ? W - 4 : gx0);
  const unsigned voff = (unsigned)((gyc * W + gx0c) * 4);  // bytes, ci-invariant

  f32x4 L[16];
  asm volatile(
      "global_load_dwordx4 %0, %8, %9\n\t"
      "global_load_dwordx4 %1, %8, %10\n\t"
      "global_load_dwordx4 %2, %8, %11\n\t"
      "global_load_dwordx4 %3, %8, %12\n\t"
      "global_load_dwordx4 %4, %8, %13\n\t"
      "global_load_dwordx4 %5, %8, %14\n\t"
      "global_load_dwordx4 %6, %8, %15\n\t"
      "global_load_dwordx4 %7, %8, %16\n\t"
      : "=&v"(L[0]), "=&v"(L[1]), "=&v"(L[2]), "=&v"(L[3]),
        "=&v"(L[4]), "=&v"(L[5]), "=&v"(L[6]), "=&v"(L[7])
      : "v"(voff), "s"(x), "s"(x + HW), "s"(x + 2 * HW), "s"(x + 3 * HW),
        "s"(x + 4 * HW), "s"(x + 5 * HW), "s"(x + 6 * HW), "s"(x + 7 * HW));
  asm volatile(
      "global_load_dwordx4 %0, %8, %9\n\t"
      "global_load_dwordx4 %1, %8, %10\n\t"
      "global_load_dwordx4 %2, %8, %11\n\t"
      "global_load_dwordx4 %3, %8, %12\n\t"
      "global_load_dwordx4 %4, %8, %13\n\t"
      "global_load_dwordx4 %5, %8, %14\n\t"
      "global_load_dwordx4 %6, %8, %15\n\t"
      "global_load_dwordx4 %7, %8, %16\n\t"
      : "=&v"(L[8]), "=&v"(L[9]), "=&v"(L[10]), "=&v"(L[11]),
        "=&v"(L[12]), "=&v"(L[13]), "=&v"(L[14]), "=&v"(L[15])
      : "v"(voff), "s"(x + 8 * HW), "s"(x + 9 * HW), "s"(x + 10 * HW),
        "s"(x + 11 * HW), "s"(x + 12 * HW), "s"(x + 13 * HW),
        "s"(x + 14 * HW), "s"(x + 15 * HW));

  // All 16 loads in flight; drain once; fence VALU reordering (rule #18).
  asm volatile("s_waitcnt vmcnt(0)" ::: "memory");
  __builtin_amdgcn_sched_barrier(0);

#pragma unroll
  for (int i = 0; i < 4; ++i) {
    const int gx = gx0 + i;
    const int lx = gx - (colbase - 1);
    if ((unsigned)lx < (unsigned)LCOLS) {
      const float fm = rowm * (((unsigned)gx < (unsigned)W) ? 1.f : 0.f);
      const int lb = (ly * LPITCH + lx * 32) ^ (((lx >> 2) & 3) << 4);
#pragma unroll
      for (int h = 0; h < 2; ++h) {
        uint4v d;
#pragma unroll
        for (int p = 0; p < 4; ++p) {
          const unsigned lo = f2bf(L[h * 8 + 2 * p][i] * fm);
          const unsigned hi = f2bf(L[h * 8 + 2 * p + 1][i] * fm);
          d[p] = lo | (hi << 16);
        }
        *(uint4v*)(lds + (lb ^ (h << 4))) = d;
      }
    }
  }
}

__global__ __launch_bounds__(256, 6) void conv_mfma(
    const float* __restrict__ x, const unsigned short* __restrict__ wA,
    float* __restrict__ out) {
  __shared__ __align__(16) char lds[LDS_BYTES];

  const int tid  = threadIdx.x;
  const int lane = tid & 63;
  const int wave = tid >> 6;
  const int m = lane & 15;   // A row = pixel within 16-px group
  const int q = lane >> 4;   // k-quarter
  const int colbase = blockIdx.x * TW;
  const int rowbase = blockIdx.y * TH;

  // ---- stage: one job per thread (204 jobs) ----
  if (tid < NJOBS) stage_job(tid, x, colbase, rowbase, lds);

  // ---- weight fragments: 5 x 16B uniform cached loads ----
  ushort8 wU[5];
#pragma unroll
  for (int p = 0; p < 5; ++p)
    wU[p] = *(const ushort8*)&wA[(p * 64 + lane) * 8];

  // ---- per-lane LDS read base addresses (wave owns one output row) ----
  int baseaddr[5];
#pragma unroll
  for (int p = 0; p < 5; ++p) {
    int t = 2 * p + (q >> 1);
    int ky = 0, kx = 0;
    if (t <= 8) { ky = t / 3; kx = t - ky * 3; }  // t==9: valid addr, zero weights
    int col = m + kx;
    int b = ky * LPITCH + col * 32 + (q & 1) * 16;
    b ^= ((col >> 2) & 3) << 4;
    baseaddr[p] = b + wave * LPITCH;
  }

  __syncthreads();

  // ---- compute: wave -> row (rowbase+wave), 8 groups of 16 px ----
#pragma unroll
  for (int g = 0; g < 8; ++g) {
    f32x4 acc = {0.f, 0.f, 0.f, 0.f};
#pragma unroll
    for (int p = 0; p < 5; ++p) {
      ushort8 bU = *(const ushort8*)(lds + (baseaddr[p] + g * 512));
      acc = __builtin_amdgcn_mfma_f32_16x16x32_bf16(
          __builtin_bit_cast(bf16x8, bU),       // A = pixels
          __builtin_bit_cast(bf16x8, wU[p]),    // B = weights
          acc, 0, 0, 0);
    }
    // D: col = lane&15 = c_out, row = q*4+j = pixel -> float4 store of 4
    // consecutive pixels for one channel.
    const int y  = rowbase + wave;
    const int x0 = colbase + g * 16 + q * 4;
    *(f32x4*)(out + m * HW + y * W + x0) = acc;
  }
}

extern "C" void kernel_launch(void* const* d_in, const int* in_sizes, int n_in,
                              void* d_out, int out_size, void* d_ws, size_t ws_size,
                              hipStream_t stream) {
  const float* x = (const float*)d_in[0];            // (1,16,1024,1024) fp32
  const float* w = (const float*)d_in[1];            // (16,16,3,3) fp32
  float* out = (float*)d_out;                        // (16,1024,1024) fp32
  unsigned short* wA = (unsigned short*)d_ws;        // 2560 ushorts = 5120 B

  conv_prep<<<10, 256, 0, stream>>>(w, wA);

  dim3 grid(W / TW, H / TH);                         // 8 x 256 = 2048 blocks
  conv_mfma<<<grid, 256, 0, stream>>>(x, wA, out);
}